// Round 4
// baseline (87.854 us; speedup 1.0000x reference)
//
#include <hip/hip_runtime.h>
#include <math.h>

#define H 128
#define W 128
#define BATCH 2
#define PIX 16

typedef short short8 __attribute__((ext_vector_type(8)));
typedef float f32x4 __attribute__((ext_vector_type(4)));

// ws layout (ushort units):
//  XS planes: 3 x padded NHWC bf16 [2][130][130][64]  (h, m, l split of x)
//  wc16 [64][576] (k-order n*64+ci), wmeta 3 planes [32][576] (k-order s*64+ci)
#define BPLANE 1081600            // per-batch plane ushorts: 130*130*64
#define PLANE  2163200            // full plane (2 batches)
#define XS_M   PLANE
#define XS_L   (2 * PLANE)
#define WC_OFF (3 * PLANE)        // 6489600
#define WM_OFF (WC_OFF + 36864)
#define WM_PLANE 18432
// total = 6581760 ushort = 12.6 MB

__device__ __forceinline__ unsigned f2bf_u(float f) {   // RNE bf16 in low 16 bits
    union { float f; unsigned u; } v; v.f = f;
    return (v.u + 0x7FFFu + ((v.u >> 16) & 1u)) >> 16;
}
__device__ __forceinline__ float bfbits2f(unsigned lo16) {
    union { unsigned u; float f; } v; v.u = lo16 << 16;
    return v.f;
}
__device__ __forceinline__ float bfs2f(short s) {
    union { unsigned u; float f; } v; v.u = ((unsigned)(unsigned short)s) << 16;
    return v.f;
}
// exact 3-way bf16 split: v == h + m + l (residuals exactly representable)
__device__ __forceinline__ void split3(float v, unsigned& h, unsigned& m, unsigned& l) {
    h = f2bf_u(v);
    float r1 = v - bfbits2f(h);
    m = f2bf_u(r1);
    float r2 = r1 - bfbits2f(m);
    l = f2bf_u(r2);
}

__global__ __launch_bounds__(256) void prep_kernel(
    const float* __restrict__ x, const float* __restrict__ w_p,
    const float* __restrict__ w_m, const float* __restrict__ w_ad,
    const float* __restrict__ w_conv, unsigned short* __restrict__ ws)
{
    const int blk = blockIdx.x, t = threadIdx.x;
    if (blk < 260) {
        // build padded split planes of x: NCHW fp32 -> 3 x NHWC bf16 [130][130][64]
        int b = blk / 130, hrow = blk % 130;
        size_t rb = ((size_t)b * 16900 + hrow * 130) * 32;   // u32 units
        unsigned* uh = (unsigned*)ws + rb;
        unsigned* um = (unsigned*)(ws + XS_M) + rb;
        unsigned* ul = (unsigned*)(ws + XS_L) + rb;
        if (hrow == 0 || hrow == 129) {
            for (int f = t; f < 4160; f += 256) { uh[f] = 0; um[f] = 0; ul[f] = 0; }
            return;
        }
        __shared__ float s[64 * 129];
        int h = hrow - 1;
        for (int f = t; f < 64 * 128; f += 256) {
            int ci = f >> 7, w = f & 127;
            s[ci * 129 + w] = x[((b * 64 + ci) * 128 + h) * 128 + w];
        }
        __syncthreads();
        for (int f = t; f < 4096; f += 256) {
            int w = f >> 5, cip = f & 31;
            unsigned h0, m0, l0, h1, m1, l1;
            split3(s[(2 * cip) * 129 + w], h0, m0, l0);
            split3(s[(2 * cip + 1) * 129 + w], h1, m1, l1);
            int o = (w + 1) * 32 + cip;
            uh[o] = h0 | (h1 << 16);
            um[o] = m0 | (m1 << 16);
            ul[o] = l0 | (l1 << 16);
        }
        if (t < 32)      { uh[t] = 0; um[t] = 0; ul[t] = 0; }
        else if (t < 64) { int o = 129 * 32 + (t - 32); uh[o] = 0; um[o] = 0; ul[o] = 0; }
    } else if (blk < 296) {
        // w_conv reorder to k = n*64 + ci, bf16
        int q = (blk - 260) * 256 + t;           // 0..9215
        int co = q / 144, rem = q % 144, n = rem >> 4, cig = rem & 15;
        const float* src = w_conv + co * 576;
        ushort4 r;
        r.x = (unsigned short)f2bf_u(src[(cig * 4 + 0) * 9 + n]);
        r.y = (unsigned short)f2bf_u(src[(cig * 4 + 1) * 9 + n]);
        r.z = (unsigned short)f2bf_u(src[(cig * 4 + 2) * 9 + n]);
        r.w = (unsigned short)f2bf_u(src[(cig * 4 + 3) * 9 + n]);
        *(ushort4*)(ws + WC_OFF + co * 576 + n * 64 + cig * 4) = r;
    } else {
        // meta weights: k-order s*64+ci, 3-way split, rows 30/31 zero
        int q = (blk - 296) * 256 + t;           // 0..18431
        int oc = q / 576, k = q % 576;
        int s = k >> 6, ci = k & 63;
        float v = 0.f;
        if (oc < 18)      v = w_p[oc * 576 + ci * 9 + s];
        else if (oc < 21) v = w_ad[(oc - 18) * 576 + ci * 9 + s];
        else if (oc < 30) v = w_m[(oc - 21) * 576 + ci * 9 + s];
        unsigned hh, mm, ll; split3(v, hh, mm, ll);
        ws[WM_OFF + q] = (unsigned short)hh;
        ws[WM_OFF + WM_PLANE + q] = (unsigned short)mm;
        ws[WM_OFF + 2 * WM_PLANE + q] = (unsigned short)ll;
    }
}

// LDS (floats, 5872 = 23488 B):
//  [0,4672)      s_valb bf16[16][584]  (aliases s_part[4][64][4] f32 in phase 1)
//  [4672,4960)   s_off[16][18]
//  [4960,5008)   s_adb[16][3]
//  [5008,5152)   s_mraw[16][9]
//  [5152,5728)   s_g[16][9][4]
//  [5728,5872)   s_idxp[16][9]

__global__ __launch_bounds__(256, 4) void deform_kernel(
    const float* __restrict__ b_p, const unsigned short* __restrict__ ws,
    float* __restrict__ out)
{
    __shared__ __align__(16) float smem[5872];
    float* s_part = smem;                               // [4][64][4]
    unsigned short* s_valb = (unsigned short*)smem;     // [16][584]
    float* s_off  = smem + 4672;
    float* s_adb  = smem + 4960;
    float* s_mraw = smem + 5008;
    float* s_g    = smem + 5152;
    int*   s_idxp = (int*)(smem + 5728);

    const int t   = threadIdx.x;
    const int blk = blockIdx.x;
    const int jb = blk & 7;              // W/PIX = 8
    const int i  = (blk >> 3) & 127;
    const int b  = blk >> 10;
    const int j0 = jb * PIX;
    const int wv = t >> 6, lane = t & 63, lr = lane & 15, lg = lane >> 4;
    const int tile = wv & 1, kq = wv >> 1;

    const unsigned short* xsb = ws + (size_t)b * BPLANE;   // padded h-plane, this batch

    // ---- Phase 1: meta conv, 6-pass split-bf16 MFMA, B direct from global planes ----
    {
        int off9[9];
        #pragma unroll
        for (int s = 0; s < 9; ++s) {
            int r = s / 3, c2 = s % 3;
            off9[s] = ((i + r) * 130 + (j0 + lr + c2)) * 64;   // padded indices
        }
        const unsigned short* wrow = ws + WM_OFF + (tile * 16 + lr) * 576 + lg * 8;
        f32x4 aA = {0.f, 0.f, 0.f, 0.f}, aB = {0.f, 0.f, 0.f, 0.f};
        #pragma unroll
        for (int k2 = 0; k2 < 9; ++k2) {
            int kk = kq * 9 + k2;
            const unsigned short* bp = xsb + off9[kk >> 1] + ((kk & 1) << 5) + lg * 8;
            short8 bh = *(const short8*)(bp);
            short8 bm = *(const short8*)(bp + XS_M);
            short8 bl = *(const short8*)(bp + XS_L);
            const unsigned short* wa = wrow + kk * 32;
            short8 ah = *(const short8*)(wa);
            short8 am = *(const short8*)(wa + WM_PLANE);
            short8 al = *(const short8*)(wa + 2 * WM_PLANE);
            aA = __builtin_amdgcn_mfma_f32_16x16x32_bf16(ah, bh, aA, 0, 0, 0);
            aB = __builtin_amdgcn_mfma_f32_16x16x32_bf16(ah, bm, aB, 0, 0, 0);
            aA = __builtin_amdgcn_mfma_f32_16x16x32_bf16(am, bh, aA, 0, 0, 0);
            aB = __builtin_amdgcn_mfma_f32_16x16x32_bf16(ah, bl, aB, 0, 0, 0);
            aA = __builtin_amdgcn_mfma_f32_16x16x32_bf16(am, bm, aA, 0, 0, 0);
            aB = __builtin_amdgcn_mfma_f32_16x16x32_bf16(al, bh, aB, 0, 0, 0);
        }
        aA[0] += aB[0]; aA[1] += aB[1]; aA[2] += aB[2]; aA[3] += aB[3];
        *(f32x4*)(s_part + (wv * 64 + lane) * 4) = aA;
    }
    __syncthreads();

    // combine K-split partials, apply bias / sigmoid
    #pragma unroll
    for (int half = 0; half < 2; ++half) {
        int idx = t + half * 256;
        int reg = idx & 3, ln = (idx >> 2) & 63, tl = idx >> 8;
        int row = (ln >> 4) * 4 + reg, oc = tl * 16 + row, pix = ln & 15;
        if (oc < 30) {
            float v = s_part[(tl * 64 + ln) * 4 + reg] + s_part[((tl + 2) * 64 + ln) * 4 + reg];
            if (oc < 18)      s_off[pix * 18 + oc] = v + b_p[oc];
            else if (oc < 21) s_adb[pix * 3 + (oc - 18)] = 1.f - 1.f / (1.f + expf(-v));
            else              s_mraw[pix * 9 + (oc - 21)] = v;
        }
    }
    __syncthreads();

    // ---- Phase 2: sampling corners + premultiplied bilinear*modulation weights ----
    if (t < PIX * 9) {
        int pix = t / 9; int n = t % 9;
        int ki = n / 3, kj = n % 3;
        float adb  = s_adb[pix * 3 + kj];
        float offx = s_off[pix * 18 + n];
        float offy = s_off[pix * 18 + 9 + n];
        float pnx = (float)(ki - 1), pny = (float)(kj - 1);
        float px = (float)(i + 1)        + pnx + offx + 2.f * adb * pnx;
        float py = (float)(j0 + pix + 1) + pny + offy + 2.f * adb * pny;

        float flx = floorf(px), fly = floorf(py);
        int ix0 = (int)fminf(fmaxf(flx,       0.f), 129.f);
        int ix1 = (int)fminf(fmaxf(flx + 1.f, 0.f), 129.f);
        int iy0 = (int)fminf(fmaxf(fly,       0.f), 129.f);
        int iy1 = (int)fminf(fmaxf(fly + 1.f, 0.f), 129.f);

        float ptx = (px < 1.f || px > 128.f) ? flx : px;
        float pty = (py < 1.f || py > 128.f) ? fly : py;
        ptx = fminf(fmaxf(ptx, 0.f), 129.f);
        pty = fminf(fmaxf(pty, 0.f), 129.f);

        float wxl = 1.f + (float)ix0 - ptx;
        float wxr = 1.f - ((float)ix1 - ptx);
        float wyl = 1.f + (float)iy0 - pty;
        float wyr = 1.f - ((float)iy1 - pty);

        float mraw = s_mraw[pix * 9 + n];
        float mm = (1.f / (1.f + expf(-mraw))) * (adb - 0.5f) * 4.f;

        int base = (pix * 9 + n) * 4;
        s_g[base + 0] = wxl * wyl * mm;
        s_g[base + 1] = wxr * wyr * mm;
        s_g[base + 2] = wxl * wyr * mm;
        s_g[base + 3] = wxr * wyl * mm;
        s_idxp[pix * 9 + n] = ix0 | (ix1 << 8) | (iy0 << 16) | (iy1 << 24);
    }
    __syncthreads();

    // ---- Phase 3: bilinear gathers from padded h-plane -> s_valb[pix][n*64+ci] ----
    for (int task = t; task < 1152; task += 256) {      // (n, pix, cig) — all shifts
        int n = task >> 7, pix = (task >> 3) & 15, cig = task & 7;
        int pk = s_idxp[pix * 9 + n];
        int ix0 = pk & 255, ix1 = (pk >> 8) & 255;
        int iy0 = (pk >> 16) & 255, iy1 = (pk >> 24) & 255;
        f32x4 g = *(const f32x4*)(s_g + (pix * 9 + n) * 4);
        const unsigned short* base = xsb + cig * 8;
        short8 v00 = *(const short8*)(base + (ix0 * 130 + iy0) * 64);
        short8 v11 = *(const short8*)(base + (ix1 * 130 + iy1) * 64);
        short8 v01 = *(const short8*)(base + (ix0 * 130 + iy1) * 64);
        short8 v10 = *(const short8*)(base + (ix1 * 130 + iy0) * 64);
        unsigned po[4];
        #pragma unroll
        for (int jp = 0; jp < 4; ++jp) {
            float e0 = g[0] * bfs2f(v00[2 * jp])     + g[1] * bfs2f(v11[2 * jp])
                     + g[2] * bfs2f(v01[2 * jp])     + g[3] * bfs2f(v10[2 * jp]);
            float e1 = g[0] * bfs2f(v00[2 * jp + 1]) + g[1] * bfs2f(v11[2 * jp + 1])
                     + g[2] * bfs2f(v01[2 * jp + 1]) + g[3] * bfs2f(v10[2 * jp + 1]);
            po[jp] = f2bf_u(e0) | (f2bf_u(e1) << 16);
        }
        *(uint4*)(s_valb + pix * 584 + n * 64 + cig * 8) = make_uint4(po[0], po[1], po[2], po[3]);
    }
    __syncthreads();

    // ---- Phase 4: MFMA contraction out[co][pix] ----
    {
        const unsigned short* wa = ws + WC_OFF + (wv * 16 + lr) * 576 + lg * 8;
        const unsigned short* vb = s_valb + lr * 584 + lg * 8;
        f32x4 aE = {0.f, 0.f, 0.f, 0.f}, aO = {0.f, 0.f, 0.f, 0.f};
        #pragma unroll 3
        for (int kk = 0; kk < 18; kk += 2) {
            short8 a0 = *(const short8*)(wa + kk * 32);
            short8 b0 = *(const short8*)(vb + kk * 32);
            aE = __builtin_amdgcn_mfma_f32_16x16x32_bf16(a0, b0, aE, 0, 0, 0);
            short8 a1 = *(const short8*)(wa + kk * 32 + 32);
            short8 b1 = *(const short8*)(vb + kk * 32 + 32);
            aO = __builtin_amdgcn_mfma_f32_16x16x32_bf16(a1, b1, aO, 0, 0, 0);
        }
        #pragma unroll
        for (int r = 0; r < 4; ++r)
            out[(((size_t)b * 64 + wv * 16 + lg * 4 + r) * 128 + i) * 128 + j0 + lr] = aE[r] + aO[r];
    }
}

extern "C" void kernel_launch(void* const* d_in, const int* in_sizes, int n_in,
                              void* d_out, int out_size, void* d_ws, size_t ws_size,
                              hipStream_t stream) {
    const float* x      = (const float*)d_in[0];
    const float* w_p    = (const float*)d_in[1];
    const float* b_p    = (const float*)d_in[2];
    const float* w_m    = (const float*)d_in[3];
    const float* w_ad   = (const float*)d_in[4];
    const float* w_conv = (const float*)d_in[5];
    float* outp = (float*)d_out;
    unsigned short* ws = (unsigned short*)d_ws;

    prep_kernel<<<368, 256, 0, stream>>>(x, w_p, w_m, w_ad, w_conv, ws);
    dim3 grid(BATCH * H * (W / PIX));
    deform_kernel<<<grid, 256, 0, stream>>>(b_p, ws, outp);
}

// Round 5
// 56.056 us; speedup vs baseline: 1.5673x; 1.5673x over previous
//
#include <hip/hip_runtime.h>
#include <math.h>

#define H 128
#define W 128
#define BATCH 2

typedef short short8 __attribute__((ext_vector_type(8)));
typedef float f32x4 __attribute__((ext_vector_type(4)));

// ws layout (ushort units):
//  XS planes: 3 x padded NHWC bf16 [2][130][130][64] (h, m, l split of x)
//  wc16 [64][576] (k-order n*64+ci), wmeta 3 planes [32][576] (k-order s*64+ci)
//  meta fp32 [2][128][128][32] at META_OFF (ushort idx; byte = 2*META_OFF, 16-aligned)
#define BPLANE 1081600
#define PLANE  2163200
#define XS_M   PLANE
#define XS_L   (2 * PLANE)
#define WC_OFF (3 * PLANE)
#define WM_OFF (WC_OFF + 36864)
#define WM_PLANE 18432
#define META_OFF (WM_OFF + 3 * WM_PLANE)
// total ws = 13.16 MB + 4.19 MB meta = 17.4 MB

__device__ __forceinline__ unsigned f2bf_u(float f) {   // RNE bf16 in low 16 bits
    union { float f; unsigned u; } v; v.f = f;
    return (v.u + 0x7FFFu + ((v.u >> 16) & 1u)) >> 16;
}
__device__ __forceinline__ float bfbits2f(unsigned lo16) {
    union { unsigned u; float f; } v; v.u = lo16 << 16;
    return v.f;
}
__device__ __forceinline__ float bfs2f(short s) {
    union { unsigned u; float f; } v; v.u = ((unsigned)(unsigned short)s) << 16;
    return v.f;
}
// exact 3-way bf16 split: v == h + m + l
__device__ __forceinline__ void split3(float v, unsigned& h, unsigned& m, unsigned& l) {
    h = f2bf_u(v);
    float r1 = v - bfbits2f(h);
    m = f2bf_u(r1);
    float r2 = r1 - bfbits2f(m);
    l = f2bf_u(r2);
}

__global__ __launch_bounds__(256) void prep_kernel(
    const float* __restrict__ x, const float* __restrict__ w_p,
    const float* __restrict__ w_m, const float* __restrict__ w_ad,
    const float* __restrict__ w_conv, unsigned short* __restrict__ ws)
{
    const int blk = blockIdx.x, t = threadIdx.x;
    if (blk < 520) {
        // padded split planes of x: NCHW fp32 -> 3 x NHWC bf16 [130][130][64]
        int code = blk >> 1, chalf = blk & 1;
        int b = code / 130, hrow = code % 130;
        size_t rb = ((size_t)b * 16900 + hrow * 130) * 32;   // u32 units
        unsigned* uh = (unsigned*)ws + rb;
        unsigned* um = (unsigned*)(ws + XS_M) + rb;
        unsigned* ul = (unsigned*)(ws + XS_L) + rb;
        if (hrow == 0 || hrow == 129) {
            for (int f = t + chalf * 2080; f < 2080 + chalf * 2080; f += 256) {
                uh[f] = 0; um[f] = 0; ul[f] = 0;
            }
            return;
        }
        __shared__ float s[64 * 65];
        int h = hrow - 1;
        for (int f = t; f < 64 * 64; f += 256) {
            int ci = f >> 6, w = f & 63;
            s[ci * 65 + w] = x[((b * 64 + ci) * 128 + h) * 128 + chalf * 64 + w];
        }
        __syncthreads();
        for (int f = t; f < 2048; f += 256) {
            int w = f >> 5, cip = f & 31;
            unsigned h0, m0, l0, h1, m1, l1;
            split3(s[(2 * cip) * 65 + w], h0, m0, l0);
            split3(s[(2 * cip + 1) * 65 + w], h1, m1, l1);
            int o = (chalf * 64 + w + 1) * 32 + cip;
            uh[o] = h0 | (h1 << 16);
            um[o] = m0 | (m1 << 16);
            ul[o] = l0 | (l1 << 16);
        }
        if (chalf == 0) { if (t < 32) { uh[t] = 0; um[t] = 0; ul[t] = 0; } }
        else           { if (t < 32) { int o = 129 * 32 + t; uh[o] = 0; um[o] = 0; ul[o] = 0; } }
    } else if (blk < 556) {
        // w_conv reorder to k = n*64 + ci, bf16
        int q = (blk - 520) * 256 + t;           // 0..9215
        int co = q / 144, rem = q % 144, n = rem >> 4, cig = rem & 15;
        const float* src = w_conv + co * 576;
        ushort4 r;
        r.x = (unsigned short)f2bf_u(src[(cig * 4 + 0) * 9 + n]);
        r.y = (unsigned short)f2bf_u(src[(cig * 4 + 1) * 9 + n]);
        r.z = (unsigned short)f2bf_u(src[(cig * 4 + 2) * 9 + n]);
        r.w = (unsigned short)f2bf_u(src[(cig * 4 + 3) * 9 + n]);
        *(ushort4*)(ws + WC_OFF + co * 576 + n * 64 + cig * 4) = r;
    } else {
        // meta weights: k-order s*64+ci, 3-way split, rows 30/31 zero
        int q = (blk - 556) * 256 + t;           // 0..18431
        int oc = q / 576, k = q % 576;
        int s = k >> 6, ci = k & 63;
        float v = 0.f;
        if (oc < 18)      v = w_p[oc * 576 + ci * 9 + s];
        else if (oc < 21) v = w_ad[(oc - 18) * 576 + ci * 9 + s];
        else if (oc < 30) v = w_m[(oc - 21) * 576 + ci * 9 + s];
        unsigned hh, mm, ll; split3(v, hh, mm, ll);
        ws[WM_OFF + q] = (unsigned short)hh;
        ws[WM_OFF + WM_PLANE + q] = (unsigned short)mm;
        ws[WM_OFF + 2 * WM_PLANE + q] = (unsigned short)ll;
    }
}

// meta_kernel: one block per output row. Weights in LDS (96 rows x 584 pad),
// 8 waves x 16 px, full K per wave, 6-pass split MFMA.
__global__ __launch_bounds__(512, 2) void meta_kernel(
    const float* __restrict__ b_p, const unsigned short* __restrict__ wsu,
    float* __restrict__ meta)
{
    __shared__ __align__(16) unsigned short s_w[96 * 584];   // 112128 B
    const int t = threadIdx.x;
    const int d = blockIdx.x;
    const int l = (d & 7) * 32 + (d >> 3);   // XCD-contiguous rows
    const int b = l >> 7, i = l & 127;

    #pragma unroll
    for (int it = 0; it < 14; ++it) {
        int chunk = it * 512 + t;
        if (chunk < 6912) {
            int r = chunk / 72, c8 = chunk % 72;
            *(short8*)(s_w + r * 584 + c8 * 8) =
                *(const short8*)(wsu + WM_OFF + chunk * 8);
        }
    }
    __syncthreads();

    const int wv = t >> 6, lane = t & 63, lr = lane & 15, lg = lane >> 4;
    const int px = wv * 16 + lr;
    const unsigned short* xsb = wsu + (size_t)b * BPLANE;

    f32x4 aA0 = {0,0,0,0}, aB0 = {0,0,0,0}, aA1 = {0,0,0,0}, aB1 = {0,0,0,0};
    #pragma unroll
    for (int kk = 0; kk < 18; ++kk) {
        const int s = kk >> 1;
        const unsigned short* bp = xsb + ((i + s / 3) * 130 + (px + s % 3)) * 64
                                   + ((kk & 1) << 5) + lg * 8;
        short8 bh = *(const short8*)(bp);
        short8 bm = *(const short8*)(bp + XS_M);
        short8 bl = *(const short8*)(bp + XS_L);
        const unsigned short* w0 = s_w + lr * 584 + kk * 32 + lg * 8;
        short8 ah0 = *(const short8*)(w0);
        short8 am0 = *(const short8*)(w0 + 32 * 584);
        short8 al0 = *(const short8*)(w0 + 64 * 584);
        const unsigned short* w1 = w0 + 16 * 584;
        short8 ah1 = *(const short8*)(w1);
        short8 am1 = *(const short8*)(w1 + 32 * 584);
        short8 al1 = *(const short8*)(w1 + 64 * 584);
        aA0 = __builtin_amdgcn_mfma_f32_16x16x32_bf16(ah0, bh, aA0, 0, 0, 0);
        aB0 = __builtin_amdgcn_mfma_f32_16x16x32_bf16(ah0, bm, aB0, 0, 0, 0);
        aA0 = __builtin_amdgcn_mfma_f32_16x16x32_bf16(am0, bh, aA0, 0, 0, 0);
        aB0 = __builtin_amdgcn_mfma_f32_16x16x32_bf16(ah0, bl, aB0, 0, 0, 0);
        aA0 = __builtin_amdgcn_mfma_f32_16x16x32_bf16(am0, bm, aA0, 0, 0, 0);
        aB0 = __builtin_amdgcn_mfma_f32_16x16x32_bf16(al0, bh, aB0, 0, 0, 0);
        aA1 = __builtin_amdgcn_mfma_f32_16x16x32_bf16(ah1, bh, aA1, 0, 0, 0);
        aB1 = __builtin_amdgcn_mfma_f32_16x16x32_bf16(ah1, bm, aB1, 0, 0, 0);
        aA1 = __builtin_amdgcn_mfma_f32_16x16x32_bf16(am1, bh, aA1, 0, 0, 0);
        aB1 = __builtin_amdgcn_mfma_f32_16x16x32_bf16(ah1, bl, aB1, 0, 0, 0);
        aA1 = __builtin_amdgcn_mfma_f32_16x16x32_bf16(am1, bm, aA1, 0, 0, 0);
        aB1 = __builtin_amdgcn_mfma_f32_16x16x32_bf16(al1, bh, aB1, 0, 0, 0);
    }

    float* mb = meta + (((size_t)b * 128 + i) * 128 + px) * 32;
    // tile 0: oc = lg*4 + r  (all < 16 -> bias)
    {
        const float4 bq = *(const float4*)(b_p + lg * 4);
        f32x4 o0;
        o0[0] = aA0[0] + aB0[0] + bq.x;
        o0[1] = aA0[1] + aB0[1] + bq.y;
        o0[2] = aA0[2] + aB0[2] + bq.z;
        o0[3] = aA0[3] + aB0[3] + bq.w;
        *(f32x4*)(mb + lg * 4) = o0;
    }
    // tile 1: oc = 16 + lg*4 + r  (bias / 1-sigmoid / sigmoid)
    {
        f32x4 o1;
        #pragma unroll
        for (int r = 0; r < 4; ++r) {
            int oc = 16 + lg * 4 + r;
            float v = aA1[r] + aB1[r];
            if (oc < 18)      v += b_p[oc];
            else if (oc < 21) v = 1.f - 1.f / (1.f + expf(-v));
            else              v = 1.f / (1.f + expf(-v));
            o1[r] = v;
        }
        *(f32x4*)(mb + 16 + lg * 4) = o1;
    }
}

// deform_kernel: phases 2-4 only; 16 px per block; ~24 KB LDS -> 6 blocks/CU.
__global__ __launch_bounds__(256, 6) void deform_kernel(
    const unsigned short* __restrict__ wsu, const float* __restrict__ meta,
    float* __restrict__ out)
{
    __shared__ __align__(16) unsigned short s_valb[16 * 584];
    __shared__ __align__(16) float s_meta[16 * 36];
    __shared__ __align__(16) float s_g[576];
    __shared__ int s_idxp[144];

    const int t = threadIdx.x;
    const int d = blockIdx.x;
    const int l = (d & 7) * 256 + (d >> 3);   // XCD-contiguous row bands (match meta_kernel)
    const int jb = l & 7, i = (l >> 3) & 127, b = l >> 10;
    const int j0 = jb * 16;

    // phase 0: load meta for these 16 pixels
    if (t < 128) {
        int px = t >> 3, q = t & 7;
        f32x4 v = *(const f32x4*)(meta + (((size_t)b * 128 + i) * 128 + j0) * 32 + t * 4);
        *(f32x4*)(&s_meta[px * 36 + q * 4]) = v;
    }
    __syncthreads();

    // phase 2: sampling corners + premultiplied bilinear*modulation weights
    if (t < 144) {
        int pix = t / 9, n = t % 9;
        int ki = n / 3, kj = n % 3;
        const float* mrow = s_meta + pix * 36;
        float adb  = mrow[18 + kj];
        float offx = mrow[n];
        float offy = mrow[9 + n];
        float msig = mrow[21 + n];
        float pnx = (float)(ki - 1), pny = (float)(kj - 1);
        float pxc = (float)(i + 1)        + pnx + offx + 2.f * adb * pnx;
        float pyc = (float)(j0 + pix + 1) + pny + offy + 2.f * adb * pny;

        float flx = floorf(pxc), fly = floorf(pyc);
        int ix0 = (int)fminf(fmaxf(flx,       0.f), 129.f);
        int ix1 = (int)fminf(fmaxf(flx + 1.f, 0.f), 129.f);
        int iy0 = (int)fminf(fmaxf(fly,       0.f), 129.f);
        int iy1 = (int)fminf(fmaxf(fly + 1.f, 0.f), 129.f);

        float ptx = (pxc < 1.f || pxc > 128.f) ? flx : pxc;
        float pty = (pyc < 1.f || pyc > 128.f) ? fly : pyc;
        ptx = fminf(fmaxf(ptx, 0.f), 129.f);
        pty = fminf(fmaxf(pty, 0.f), 129.f);

        float wxl = 1.f + (float)ix0 - ptx;
        float wxr = 1.f - ((float)ix1 - ptx);
        float wyl = 1.f + (float)iy0 - pty;
        float wyr = 1.f - ((float)iy1 - pty);

        float mm = msig * (adb - 0.5f) * 4.f;

        int base = t * 4;
        s_g[base + 0] = wxl * wyl * mm;
        s_g[base + 1] = wxr * wyr * mm;
        s_g[base + 2] = wxl * wyr * mm;
        s_g[base + 3] = wxr * wyl * mm;
        s_idxp[t] = ix0 | (ix1 << 8) | (iy0 << 16) | (iy1 << 24);
    }
    __syncthreads();

    // phase 3: bilinear gathers from padded h-plane -> s_valb[pix][n*64+ci]
    const unsigned short* xsb = wsu + (size_t)b * BPLANE;
    for (int task = t; task < 1152; task += 256) {
        int n = task >> 7, pix = (task >> 3) & 15, cig = task & 7;
        int pk = s_idxp[pix * 9 + n];
        int ix0 = pk & 255, ix1 = (pk >> 8) & 255;
        int iy0 = (pk >> 16) & 255, iy1 = (pk >> 24) & 255;
        f32x4 g = *(const f32x4*)(s_g + (pix * 9 + n) * 4);
        const unsigned short* base = xsb + cig * 8;
        short8 v00 = *(const short8*)(base + (ix0 * 130 + iy0) * 64);
        short8 v11 = *(const short8*)(base + (ix1 * 130 + iy1) * 64);
        short8 v01 = *(const short8*)(base + (ix0 * 130 + iy1) * 64);
        short8 v10 = *(const short8*)(base + (ix1 * 130 + iy0) * 64);
        unsigned po[4];
        #pragma unroll
        for (int jp = 0; jp < 4; ++jp) {
            float e0 = g[0] * bfs2f(v00[2 * jp])     + g[1] * bfs2f(v11[2 * jp])
                     + g[2] * bfs2f(v01[2 * jp])     + g[3] * bfs2f(v10[2 * jp]);
            float e1 = g[0] * bfs2f(v00[2 * jp + 1]) + g[1] * bfs2f(v11[2 * jp + 1])
                     + g[2] * bfs2f(v01[2 * jp + 1]) + g[3] * bfs2f(v10[2 * jp + 1]);
            po[jp] = f2bf_u(e0) | (f2bf_u(e1) << 16);
        }
        *(uint4*)(s_valb + pix * 584 + n * 64 + cig * 8) = make_uint4(po[0], po[1], po[2], po[3]);
    }
    __syncthreads();

    // phase 4: MFMA contraction out[co][pix]
    {
        const int wv = t >> 6, lane = t & 63, lr = lane & 15, lg = lane >> 4;
        const unsigned short* wa = wsu + WC_OFF + (wv * 16 + lr) * 576 + lg * 8;
        const unsigned short* vb = s_valb + lr * 584 + lg * 8;
        f32x4 aE = {0,0,0,0}, aO = {0,0,0,0};
        #pragma unroll 3
        for (int kk = 0; kk < 18; kk += 2) {
            short8 a0 = *(const short8*)(wa + kk * 32);
            short8 b0 = *(const short8*)(vb + kk * 32);
            aE = __builtin_amdgcn_mfma_f32_16x16x32_bf16(a0, b0, aE, 0, 0, 0);
            short8 a1 = *(const short8*)(wa + kk * 32 + 32);
            short8 b1 = *(const short8*)(vb + kk * 32 + 32);
            aO = __builtin_amdgcn_mfma_f32_16x16x32_bf16(a1, b1, aO, 0, 0, 0);
        }
        #pragma unroll
        for (int r = 0; r < 4; ++r)
            out[(((size_t)b * 64 + wv * 16 + lg * 4 + r) * 128 + i) * 128 + j0 + lr] = aE[r] + aO[r];
    }
}

extern "C" void kernel_launch(void* const* d_in, const int* in_sizes, int n_in,
                              void* d_out, int out_size, void* d_ws, size_t ws_size,
                              hipStream_t stream) {
    const float* x      = (const float*)d_in[0];
    const float* w_p    = (const float*)d_in[1];
    const float* b_p    = (const float*)d_in[2];
    const float* w_m    = (const float*)d_in[3];
    const float* w_ad   = (const float*)d_in[4];
    const float* w_conv = (const float*)d_in[5];
    float* outp = (float*)d_out;
    unsigned short* ws = (unsigned short*)d_ws;
    float* meta_f = (float*)(ws + META_OFF);

    prep_kernel<<<628, 256, 0, stream>>>(x, w_p, w_m, w_ad, w_conv, ws);
    meta_kernel<<<256, 512, 0, stream>>>(b_p, ws, meta_f);
    deform_kernel<<<2048, 256, 0, stream>>>(ws, meta_f, outp);
}

// Round 6
// 56.043 us; speedup vs baseline: 1.5676x; 1.0002x over previous
//
#include <hip/hip_runtime.h>
#include <math.h>

#define H 128
#define W 128
#define BATCH 2

typedef short short8 __attribute__((ext_vector_type(8)));
typedef float f32x4 __attribute__((ext_vector_type(4)));

// ws layout (ushort units):
//  XS planes: 3 x padded NHWC bf16 [2][130][130][64] (h, m, l split of x)
//  wc16 [64][576] (k-order n*64+ci), wmeta 3 planes [32][576] (k-order s*64+ci)
//  meta fp32 [2][128][128][32] at META_OFF
#define BPLANE 1081600
#define PLANE  2163200
#define XS_M   PLANE
#define XS_L   (2 * PLANE)
#define WC_OFF (3 * PLANE)
#define WM_OFF (WC_OFF + 36864)
#define WM_PLANE 18432
#define META_OFF (WM_OFF + 3 * WM_PLANE)

__device__ __forceinline__ unsigned f2bf_u(float f) {   // RNE bf16 in low 16 bits
    union { float f; unsigned u; } v; v.f = f;
    return (v.u + 0x7FFFu + ((v.u >> 16) & 1u)) >> 16;
}
__device__ __forceinline__ float bfbits2f(unsigned lo16) {
    union { unsigned u; float f; } v; v.u = lo16 << 16;
    return v.f;
}
__device__ __forceinline__ float bfs2f(short s) {
    union { unsigned u; float f; } v; v.u = ((unsigned)(unsigned short)s) << 16;
    return v.f;
}
// exact 3-way bf16 split: v == h + m + l
__device__ __forceinline__ void split3(float v, unsigned& h, unsigned& m, unsigned& l) {
    h = f2bf_u(v);
    float r1 = v - bfbits2f(h);
    m = f2bf_u(r1);
    float r2 = r1 - bfbits2f(m);
    l = f2bf_u(r2);
}

__global__ __launch_bounds__(256) void prep_kernel(
    const float* __restrict__ x, const float* __restrict__ w_p,
    const float* __restrict__ w_m, const float* __restrict__ w_ad,
    const float* __restrict__ w_conv, unsigned short* __restrict__ ws)
{
    const int blk = blockIdx.x, t = threadIdx.x;
    if (blk < 520) {
        // padded split planes of x: NCHW fp32 -> 3 x NHWC bf16 [130][130][64]
        int code = blk >> 1, chalf = blk & 1;
        int b = code / 130, hrow = code % 130;
        size_t rb = ((size_t)b * 16900 + hrow * 130) * 32;   // u32 units
        unsigned* uh = (unsigned*)ws + rb;
        unsigned* um = (unsigned*)(ws + XS_M) + rb;
        unsigned* ul = (unsigned*)(ws + XS_L) + rb;
        if (hrow == 0 || hrow == 129) {
            for (int f = t + chalf * 2080; f < 2080 + chalf * 2080; f += 256) {
                uh[f] = 0; um[f] = 0; ul[f] = 0;
            }
            return;
        }
        __shared__ float s[64 * 65];
        int h = hrow - 1;
        for (int f = t; f < 64 * 64; f += 256) {
            int ci = f >> 6, w = f & 63;
            s[ci * 65 + w] = x[((b * 64 + ci) * 128 + h) * 128 + chalf * 64 + w];
        }
        __syncthreads();
        for (int f = t; f < 2048; f += 256) {
            int w = f >> 5, cip = f & 31;
            unsigned h0, m0, l0, h1, m1, l1;
            split3(s[(2 * cip) * 65 + w], h0, m0, l0);
            split3(s[(2 * cip + 1) * 65 + w], h1, m1, l1);
            int o = (chalf * 64 + w + 1) * 32 + cip;
            uh[o] = h0 | (h1 << 16);
            um[o] = m0 | (m1 << 16);
            ul[o] = l0 | (l1 << 16);
        }
        if (chalf == 0) { if (t < 32) { uh[t] = 0; um[t] = 0; ul[t] = 0; } }
        else           { if (t < 32) { int o = 129 * 32 + t; uh[o] = 0; um[o] = 0; ul[o] = 0; } }
    } else if (blk < 556) {
        // w_conv reorder to k = n*64 + ci, bf16
        int q = (blk - 520) * 256 + t;           // 0..9215
        int co = q / 144, rem = q % 144, n = rem >> 4, cig = rem & 15;
        const float* src = w_conv + co * 576;
        ushort4 r;
        r.x = (unsigned short)f2bf_u(src[(cig * 4 + 0) * 9 + n]);
        r.y = (unsigned short)f2bf_u(src[(cig * 4 + 1) * 9 + n]);
        r.z = (unsigned short)f2bf_u(src[(cig * 4 + 2) * 9 + n]);
        r.w = (unsigned short)f2bf_u(src[(cig * 4 + 3) * 9 + n]);
        *(ushort4*)(ws + WC_OFF + co * 576 + n * 64 + cig * 4) = r;
    } else {
        // meta weights: k-order s*64+ci, 3-way split, rows 30/31 zero
        int q = (blk - 556) * 256 + t;           // 0..18431
        int oc = q / 576, k = q % 576;
        int s = k >> 6, ci = k & 63;
        float v = 0.f;
        if (oc < 18)      v = w_p[oc * 576 + ci * 9 + s];
        else if (oc < 21) v = w_ad[(oc - 18) * 576 + ci * 9 + s];
        else if (oc < 30) v = w_m[(oc - 21) * 576 + ci * 9 + s];
        unsigned hh, mm, ll; split3(v, hh, mm, ll);
        ws[WM_OFF + q] = (unsigned short)hh;
        ws[WM_OFF + WM_PLANE + q] = (unsigned short)mm;
        ws[WM_OFF + 2 * WM_PLANE + q] = (unsigned short)ll;
    }
}

// meta_kernel: one block per output row. Weights in LDS (96 rows x 584 pad),
// 8 waves x 16 px, full K per wave, 6-pass split MFMA.
__global__ __launch_bounds__(512, 2) void meta_kernel(
    const float* __restrict__ b_p, const unsigned short* __restrict__ wsu,
    float* __restrict__ meta)
{
    __shared__ __align__(16) unsigned short s_w[96 * 584];   // 112128 B
    const int t = threadIdx.x;
    const int d = blockIdx.x;
    const int l = (d & 7) * 32 + (d >> 3);   // XCD-contiguous rows
    const int b = l >> 7, i = l & 127;

    #pragma unroll
    for (int it = 0; it < 14; ++it) {
        int chunk = it * 512 + t;
        if (chunk < 6912) {
            int r = chunk / 72, c8 = chunk % 72;
            *(short8*)(s_w + r * 584 + c8 * 8) =
                *(const short8*)(wsu + WM_OFF + chunk * 8);
        }
    }
    __syncthreads();

    const int wv = t >> 6, lane = t & 63, lr = lane & 15, lg = lane >> 4;
    const int px = wv * 16 + lr;
    const unsigned short* xsb = wsu + (size_t)b * BPLANE;

    f32x4 aA0 = {0,0,0,0}, aB0 = {0,0,0,0}, aA1 = {0,0,0,0}, aB1 = {0,0,0,0};
    #pragma unroll
    for (int kk = 0; kk < 18; ++kk) {
        const int s = kk >> 1;
        const unsigned short* bp = xsb + ((i + s / 3) * 130 + (px + s % 3)) * 64
                                   + ((kk & 1) << 5) + lg * 8;
        short8 bh = *(const short8*)(bp);
        short8 bm = *(const short8*)(bp + XS_M);
        short8 bl = *(const short8*)(bp + XS_L);
        const unsigned short* w0 = s_w + lr * 584 + kk * 32 + lg * 8;
        short8 ah0 = *(const short8*)(w0);
        short8 am0 = *(const short8*)(w0 + 32 * 584);
        short8 al0 = *(const short8*)(w0 + 64 * 584);
        const unsigned short* w1 = w0 + 16 * 584;
        short8 ah1 = *(const short8*)(w1);
        short8 am1 = *(const short8*)(w1 + 32 * 584);
        short8 al1 = *(const short8*)(w1 + 64 * 584);
        aA0 = __builtin_amdgcn_mfma_f32_16x16x32_bf16(ah0, bh, aA0, 0, 0, 0);
        aB0 = __builtin_amdgcn_mfma_f32_16x16x32_bf16(ah0, bm, aB0, 0, 0, 0);
        aA0 = __builtin_amdgcn_mfma_f32_16x16x32_bf16(am0, bh, aA0, 0, 0, 0);
        aB0 = __builtin_amdgcn_mfma_f32_16x16x32_bf16(ah0, bl, aB0, 0, 0, 0);
        aA0 = __builtin_amdgcn_mfma_f32_16x16x32_bf16(am0, bm, aA0, 0, 0, 0);
        aB0 = __builtin_amdgcn_mfma_f32_16x16x32_bf16(al0, bh, aB0, 0, 0, 0);
        aA1 = __builtin_amdgcn_mfma_f32_16x16x32_bf16(ah1, bh, aA1, 0, 0, 0);
        aB1 = __builtin_amdgcn_mfma_f32_16x16x32_bf16(ah1, bm, aB1, 0, 0, 0);
        aA1 = __builtin_amdgcn_mfma_f32_16x16x32_bf16(am1, bh, aA1, 0, 0, 0);
        aB1 = __builtin_amdgcn_mfma_f32_16x16x32_bf16(ah1, bl, aB1, 0, 0, 0);
        aA1 = __builtin_amdgcn_mfma_f32_16x16x32_bf16(am1, bm, aA1, 0, 0, 0);
        aB1 = __builtin_amdgcn_mfma_f32_16x16x32_bf16(al1, bh, aB1, 0, 0, 0);
    }

    float* mb = meta + (((size_t)b * 128 + i) * 128 + px) * 32;
    {
        const float4 bq = *(const float4*)(b_p + lg * 4);
        f32x4 o0;
        o0[0] = aA0[0] + aB0[0] + bq.x;
        o0[1] = aA0[1] + aB0[1] + bq.y;
        o0[2] = aA0[2] + aB0[2] + bq.z;
        o0[3] = aA0[3] + aB0[3] + bq.w;
        *(f32x4*)(mb + lg * 4) = o0;
    }
    {
        f32x4 o1;
        #pragma unroll
        for (int r = 0; r < 4; ++r) {
            int oc = 16 + lg * 4 + r;
            float v = aA1[r] + aB1[r];
            if (oc < 18)      v += b_p[oc];
            else if (oc < 21) v = 1.f - 1.f / (1.f + expf(-v));
            else              v = 1.f / (1.f + expf(-v));
            o1[r] = v;
        }
        *(f32x4*)(mb + 16 + lg * 4) = o1;
    }
}

// deform_kernel: 32 px per block, 512 threads (8 waves = 4 co-tiles x 2 px-tiles).
// LDS ~47.7 KB -> 3 blocks/CU.
__global__ __launch_bounds__(512, 6) void deform_kernel(
    const unsigned short* __restrict__ wsu, const float* __restrict__ meta,
    float* __restrict__ out)
{
    __shared__ __align__(16) unsigned short s_valb[32 * 584];   // 37376 B
    __shared__ __align__(16) float s_meta[32 * 36];
    __shared__ __align__(16) float s_g[32 * 9 * 4];
    __shared__ int s_idxp[32 * 9];

    const int t = threadIdx.x;
    const int d = blockIdx.x;
    const int l = (d & 7) * 128 + (d >> 3);   // XCD-contiguous bands (match meta_kernel)
    const int jb = l & 3, i = (l >> 2) & 127, b = l >> 9;
    const int j0 = jb * 32;

    // phase 0: load meta for these 32 pixels
    if (t < 256) {
        int px = t >> 3, q = t & 7;
        f32x4 v = *(const f32x4*)(meta + (((size_t)b * 128 + i) * 128 + j0) * 32 + t * 4);
        *(f32x4*)(&s_meta[px * 36 + q * 4]) = v;
    }
    __syncthreads();

    // phase 2: sampling corners + premultiplied bilinear*modulation weights
    if (t < 288) {
        int pix = t / 9, n = t % 9;
        int ki = n / 3, kj = n % 3;
        const float* mrow = s_meta + pix * 36;
        float adb  = mrow[18 + kj];
        float offx = mrow[n];
        float offy = mrow[9 + n];
        float msig = mrow[21 + n];
        float pnx = (float)(ki - 1), pny = (float)(kj - 1);
        float pxc = (float)(i + 1)        + pnx + offx + 2.f * adb * pnx;
        float pyc = (float)(j0 + pix + 1) + pny + offy + 2.f * adb * pny;

        float flx = floorf(pxc), fly = floorf(pyc);
        int ix0 = (int)fminf(fmaxf(flx,       0.f), 129.f);
        int ix1 = (int)fminf(fmaxf(flx + 1.f, 0.f), 129.f);
        int iy0 = (int)fminf(fmaxf(fly,       0.f), 129.f);
        int iy1 = (int)fminf(fmaxf(fly + 1.f, 0.f), 129.f);

        float ptx = (pxc < 1.f || pxc > 128.f) ? flx : pxc;
        float pty = (pyc < 1.f || pyc > 128.f) ? fly : pyc;
        ptx = fminf(fmaxf(ptx, 0.f), 129.f);
        pty = fminf(fmaxf(pty, 0.f), 129.f);

        float wxl = 1.f + (float)ix0 - ptx;
        float wxr = 1.f - ((float)ix1 - ptx);
        float wyl = 1.f + (float)iy0 - pty;
        float wyr = 1.f - ((float)iy1 - pty);

        float mm = msig * (adb - 0.5f) * 4.f;

        int base = t * 4;
        s_g[base + 0] = wxl * wyl * mm;
        s_g[base + 1] = wxr * wyr * mm;
        s_g[base + 2] = wxl * wyr * mm;
        s_g[base + 3] = wxr * wyl * mm;
        s_idxp[t] = ix0 | (ix1 << 8) | (iy0 << 16) | (iy1 << 24);
    }
    __syncthreads();

    // phase 3: bilinear gathers from padded h-plane -> s_valb[pix][n*64+ci]
    const unsigned short* xsb = wsu + (size_t)b * BPLANE;
    for (int task = t; task < 2304; task += 512) {
        int n = task >> 8, pix = (task >> 3) & 31, cig = task & 7;
        int pk = s_idxp[pix * 9 + n];
        int ix0 = pk & 255, ix1 = (pk >> 8) & 255;
        int iy0 = (pk >> 16) & 255, iy1 = (pk >> 24) & 255;
        f32x4 g = *(const f32x4*)(s_g + (pix * 9 + n) * 4);
        const unsigned short* base = xsb + cig * 8;
        short8 v00 = *(const short8*)(base + (ix0 * 130 + iy0) * 64);
        short8 v11 = *(const short8*)(base + (ix1 * 130 + iy1) * 64);
        short8 v01 = *(const short8*)(base + (ix0 * 130 + iy1) * 64);
        short8 v10 = *(const short8*)(base + (ix1 * 130 + iy0) * 64);
        unsigned po[4];
        #pragma unroll
        for (int jp = 0; jp < 4; ++jp) {
            float e0 = g[0] * bfs2f(v00[2 * jp])     + g[1] * bfs2f(v11[2 * jp])
                     + g[2] * bfs2f(v01[2 * jp])     + g[3] * bfs2f(v10[2 * jp]);
            float e1 = g[0] * bfs2f(v00[2 * jp + 1]) + g[1] * bfs2f(v11[2 * jp + 1])
                     + g[2] * bfs2f(v01[2 * jp + 1]) + g[3] * bfs2f(v10[2 * jp + 1]);
            po[jp] = f2bf_u(e0) | (f2bf_u(e1) << 16);
        }
        *(uint4*)(s_valb + pix * 584 + n * 64 + cig * 8) = make_uint4(po[0], po[1], po[2], po[3]);
    }
    __syncthreads();

    // phase 4: MFMA contraction; wave (ct, pt): co-tile ct, px-tile pt
    {
        const int wv = t >> 6, lane = t & 63, lr = lane & 15, lg = lane >> 4;
        const int ct = wv & 3, pt = wv >> 2;
        const unsigned short* wa = wsu + WC_OFF + (ct * 16 + lr) * 576 + lg * 8;
        const unsigned short* vb = s_valb + (pt * 16 + lr) * 584 + lg * 8;
        f32x4 aE = {0,0,0,0}, aO = {0,0,0,0};
        #pragma unroll 3
        for (int kk = 0; kk < 18; kk += 2) {
            short8 a0 = *(const short8*)(wa + kk * 32);
            short8 b0 = *(const short8*)(vb + kk * 32);
            aE = __builtin_amdgcn_mfma_f32_16x16x32_bf16(a0, b0, aE, 0, 0, 0);
            short8 a1 = *(const short8*)(wa + kk * 32 + 32);
            short8 b1 = *(const short8*)(vb + kk * 32 + 32);
            aO = __builtin_amdgcn_mfma_f32_16x16x32_bf16(a1, b1, aO, 0, 0, 0);
        }
        #pragma unroll
        for (int r = 0; r < 4; ++r)
            out[(((size_t)b * 64 + ct * 16 + lg * 4 + r) * 128 + i) * 128 + j0 + pt * 16 + lr]
                = aE[r] + aO[r];
    }
}

extern "C" void kernel_launch(void* const* d_in, const int* in_sizes, int n_in,
                              void* d_out, int out_size, void* d_ws, size_t ws_size,
                              hipStream_t stream) {
    const float* x      = (const float*)d_in[0];
    const float* w_p    = (const float*)d_in[1];
    const float* b_p    = (const float*)d_in[2];
    const float* w_m    = (const float*)d_in[3];
    const float* w_ad   = (const float*)d_in[4];
    const float* w_conv = (const float*)d_in[5];
    float* outp = (float*)d_out;
    unsigned short* ws = (unsigned short*)d_ws;
    float* meta_f = (float*)(ws + META_OFF);

    prep_kernel<<<628, 256, 0, stream>>>(x, w_p, w_m, w_ad, w_conv, ws);
    meta_kernel<<<256, 512, 0, stream>>>(b_p, ws, meta_f);
    deform_kernel<<<1024, 512, 0, stream>>>(ws, meta_f, outp);
}

// Round 7
// 48.213 us; speedup vs baseline: 1.8222x; 1.1624x over previous
//
#include <hip/hip_runtime.h>
#include <math.h>

#define H 128
#define W 128
#define BATCH 2

typedef short short8 __attribute__((ext_vector_type(8)));
typedef float f32x4 __attribute__((ext_vector_type(4)));

// ws layout (ushort units):
//  XS planes: 2 x padded NHWC bf16 [2][130][130][64] (h, m split of x)
//  wc16 [64][576] (k-order n*64+ci), wmeta 2 planes [32][576] (k-order s*64+ci)
//  meta fp32 [2][128][128][32] at META_OFF
#define BPLANE 1081600
#define PLANE  2163200
#define XS_M   PLANE
#define WC_OFF (2 * PLANE)            // 4326400
#define WM_OFF (WC_OFF + 36864)       // 4363264
#define WM_PLANE 18432
#define META_OFF (WM_OFF + 2 * WM_PLANE)

__device__ __forceinline__ unsigned f2bf_u(float f) {   // RNE bf16 in low 16 bits
    union { float f; unsigned u; } v; v.f = f;
    return (v.u + 0x7FFFu + ((v.u >> 16) & 1u)) >> 16;
}
__device__ __forceinline__ float bfbits2f(unsigned lo16) {
    union { unsigned u; float f; } v; v.u = lo16 << 16;
    return v.f;
}
__device__ __forceinline__ float bfs2f(short s) {
    union { unsigned u; float f; } v; v.u = ((unsigned)(unsigned short)s) << 16;
    return v.f;
}
// 2-way bf16 split: v ~= h + m (residual ~2^-17 relative)
__device__ __forceinline__ void split2(float v, unsigned& h, unsigned& m) {
    h = f2bf_u(v);
    float r1 = v - bfbits2f(h);
    m = f2bf_u(r1);
}

__global__ __launch_bounds__(256) void prep_kernel(
    const float* __restrict__ x, const float* __restrict__ w_p,
    const float* __restrict__ w_m, const float* __restrict__ w_ad,
    const float* __restrict__ w_conv, unsigned short* __restrict__ ws)
{
    const int blk = blockIdx.x, t = threadIdx.x;
    if (blk < 520) {
        // padded split planes of x: NCHW fp32 -> 2 x NHWC bf16 [130][130][64]
        int code = blk >> 1, chalf = blk & 1;
        int b = code / 130, hrow = code % 130;
        size_t rb = ((size_t)b * 16900 + hrow * 130) * 32;   // u32 units
        unsigned* uh = (unsigned*)ws + rb;
        unsigned* um = (unsigned*)(ws + XS_M) + rb;
        if (hrow == 0 || hrow == 129) {
            for (int f = t + chalf * 2080; f < 2080 + chalf * 2080; f += 256) {
                uh[f] = 0; um[f] = 0;
            }
            return;
        }
        __shared__ float s[64 * 65];
        int h = hrow - 1;
        for (int f = t; f < 64 * 64; f += 256) {
            int ci = f >> 6, w = f & 63;
            s[ci * 65 + w] = x[((b * 64 + ci) * 128 + h) * 128 + chalf * 64 + w];
        }
        __syncthreads();
        for (int f = t; f < 2048; f += 256) {
            int w = f >> 5, cip = f & 31;
            unsigned h0, m0, h1, m1;
            split2(s[(2 * cip) * 65 + w], h0, m0);
            split2(s[(2 * cip + 1) * 65 + w], h1, m1);
            int o = (chalf * 64 + w + 1) * 32 + cip;
            uh[o] = h0 | (h1 << 16);
            um[o] = m0 | (m1 << 16);
        }
        if (chalf == 0) { if (t < 32) { uh[t] = 0; um[t] = 0; } }
        else           { if (t < 32) { int o = 129 * 32 + t; uh[o] = 0; um[o] = 0; } }
    } else if (blk < 556) {
        // w_conv reorder to k = n*64 + ci, bf16
        int q = (blk - 520) * 256 + t;           // 0..9215
        int co = q / 144, rem = q % 144, n = rem >> 4, cig = rem & 15;
        const float* src = w_conv + co * 576;
        ushort4 r;
        r.x = (unsigned short)f2bf_u(src[(cig * 4 + 0) * 9 + n]);
        r.y = (unsigned short)f2bf_u(src[(cig * 4 + 1) * 9 + n]);
        r.z = (unsigned short)f2bf_u(src[(cig * 4 + 2) * 9 + n]);
        r.w = (unsigned short)f2bf_u(src[(cig * 4 + 3) * 9 + n]);
        *(ushort4*)(ws + WC_OFF + co * 576 + n * 64 + cig * 4) = r;
    } else {
        // meta weights: k-order s*64+ci, 2-way split, rows 30/31 zero
        int q = (blk - 556) * 256 + t;           // 0..18431
        int oc = q / 576, k = q % 576;
        int s = k >> 6, ci = k & 63;
        float v = 0.f;
        if (oc < 18)      v = w_p[oc * 576 + ci * 9 + s];
        else if (oc < 21) v = w_ad[(oc - 18) * 576 + ci * 9 + s];
        else if (oc < 30) v = w_m[(oc - 21) * 576 + ci * 9 + s];
        unsigned hh, mm; split2(v, hh, mm);
        ws[WM_OFF + q] = (unsigned short)hh;
        ws[WM_OFF + WM_PLANE + q] = (unsigned short)mm;
    }
}

// meta_kernel: one block per output row. Weights in LDS (64 rows x 584 pad = 73 KB),
// 8 waves x 16 px, full K per wave, 3-pass split MFMA (h*h + h*m + m*h).
__global__ __launch_bounds__(512, 2) void meta_kernel(
    const float* __restrict__ b_p, const unsigned short* __restrict__ wsu,
    float* __restrict__ meta)
{
    __shared__ __align__(16) unsigned short s_w[64 * 584];   // 74752 B
    const int t = threadIdx.x;
    const int d = blockIdx.x;
    const int l = (d & 7) * 32 + (d >> 3);   // XCD-contiguous rows
    const int b = l >> 7, i = l & 127;

    #pragma unroll
    for (int it = 0; it < 9; ++it) {
        int chunk = it * 512 + t;            // 4608 chunks of 8 ushort
        int r = chunk / 72, c8 = chunk % 72;
        *(short8*)(s_w + r * 584 + c8 * 8) =
            *(const short8*)(wsu + WM_OFF + chunk * 8);
    }
    __syncthreads();

    const int wv = t >> 6, lane = t & 63, lr = lane & 15, lg = lane >> 4;
    const int px = wv * 16 + lr;
    const unsigned short* xsb = wsu + (size_t)b * BPLANE;

    f32x4 aA0 = {0,0,0,0}, aB0 = {0,0,0,0}, aA1 = {0,0,0,0}, aB1 = {0,0,0,0};
    #pragma unroll
    for (int kk = 0; kk < 18; ++kk) {
        const int s = kk >> 1;
        const unsigned short* bp = xsb + ((i + s / 3) * 130 + (px + s % 3)) * 64
                                   + ((kk & 1) << 5) + lg * 8;
        short8 bh = *(const short8*)(bp);
        short8 bm = *(const short8*)(bp + XS_M);
        const unsigned short* w0 = s_w + lr * 584 + kk * 32 + lg * 8;
        short8 ah0 = *(const short8*)(w0);
        short8 am0 = *(const short8*)(w0 + 32 * 584);
        const unsigned short* w1 = w0 + 16 * 584;
        short8 ah1 = *(const short8*)(w1);
        short8 am1 = *(const short8*)(w1 + 32 * 584);
        aA0 = __builtin_amdgcn_mfma_f32_16x16x32_bf16(ah0, bh, aA0, 0, 0, 0);
        aB0 = __builtin_amdgcn_mfma_f32_16x16x32_bf16(ah0, bm, aB0, 0, 0, 0);
        aA0 = __builtin_amdgcn_mfma_f32_16x16x32_bf16(am0, bh, aA0, 0, 0, 0);
        aA1 = __builtin_amdgcn_mfma_f32_16x16x32_bf16(ah1, bh, aA1, 0, 0, 0);
        aB1 = __builtin_amdgcn_mfma_f32_16x16x32_bf16(ah1, bm, aB1, 0, 0, 0);
        aA1 = __builtin_amdgcn_mfma_f32_16x16x32_bf16(am1, bh, aA1, 0, 0, 0);
    }

    float* mb = meta + (((size_t)b * 128 + i) * 128 + px) * 32;
    {
        const float4 bq = *(const float4*)(b_p + lg * 4);
        f32x4 o0;
        o0[0] = aA0[0] + aB0[0] + bq.x;
        o0[1] = aA0[1] + aB0[1] + bq.y;
        o0[2] = aA0[2] + aB0[2] + bq.z;
        o0[3] = aA0[3] + aB0[3] + bq.w;
        *(f32x4*)(mb + lg * 4) = o0;
    }
    {
        f32x4 o1;
        #pragma unroll
        for (int r = 0; r < 4; ++r) {
            int oc = 16 + lg * 4 + r;
            float v = aA1[r] + aB1[r];
            if (oc < 18)      v += b_p[oc];
            else if (oc < 21) v = 1.f - 1.f / (1.f + expf(-v));
            else              v = 1.f / (1.f + expf(-v));
            o1[r] = v;
        }
        *(f32x4*)(mb + 16 + lg * 4) = o1;
    }
}

// deform_kernel: 32 px per block, 512 threads (8 waves = 4 co-tiles x 2 px-tiles).
__global__ __launch_bounds__(512, 6) void deform_kernel(
    const unsigned short* __restrict__ wsu, const float* __restrict__ meta,
    float* __restrict__ out)
{
    __shared__ __align__(16) unsigned short s_valb[32 * 584];   // 37376 B
    __shared__ __align__(16) float s_meta[32 * 36];
    __shared__ __align__(16) float s_g[32 * 9 * 4];
    __shared__ int s_idxp[32 * 9];

    const int t = threadIdx.x;
    const int d = blockIdx.x;
    const int l = (d & 7) * 128 + (d >> 3);   // XCD-contiguous bands (match meta_kernel)
    const int jb = l & 3, i = (l >> 2) & 127, b = l >> 9;
    const int j0 = jb * 32;

    // phase 0: load meta for these 32 pixels
    if (t < 256) {
        int px = t >> 3, q = t & 7;
        f32x4 v = *(const f32x4*)(meta + (((size_t)b * 128 + i) * 128 + j0) * 32 + t * 4);
        *(f32x4*)(&s_meta[px * 36 + q * 4]) = v;
    }
    __syncthreads();

    // phase 2: sampling corners + premultiplied bilinear*modulation weights
    if (t < 288) {
        int pix = t / 9, n = t % 9;
        int ki = n / 3, kj = n % 3;
        const float* mrow = s_meta + pix * 36;
        float adb  = mrow[18 + kj];
        float offx = mrow[n];
        float offy = mrow[9 + n];
        float msig = mrow[21 + n];
        float pnx = (float)(ki - 1), pny = (float)(kj - 1);
        float pxc = (float)(i + 1)        + pnx + offx + 2.f * adb * pnx;
        float pyc = (float)(j0 + pix + 1) + pny + offy + 2.f * adb * pny;

        float flx = floorf(pxc), fly = floorf(pyc);
        int ix0 = (int)fminf(fmaxf(flx,       0.f), 129.f);
        int ix1 = (int)fminf(fmaxf(flx + 1.f, 0.f), 129.f);
        int iy0 = (int)fminf(fmaxf(fly,       0.f), 129.f);
        int iy1 = (int)fminf(fmaxf(fly + 1.f, 0.f), 129.f);

        float ptx = (pxc < 1.f || pxc > 128.f) ? flx : pxc;
        float pty = (pyc < 1.f || pyc > 128.f) ? fly : pyc;
        ptx = fminf(fmaxf(ptx, 0.f), 129.f);
        pty = fminf(fmaxf(pty, 0.f), 129.f);

        float wxl = 1.f + (float)ix0 - ptx;
        float wxr = 1.f - ((float)ix1 - ptx);
        float wyl = 1.f + (float)iy0 - pty;
        float wyr = 1.f - ((float)iy1 - pty);

        float mm = msig * (adb - 0.5f) * 4.f;

        int base = t * 4;
        s_g[base + 0] = wxl * wyl * mm;
        s_g[base + 1] = wxr * wyr * mm;
        s_g[base + 2] = wxl * wyr * mm;
        s_g[base + 3] = wxr * wyl * mm;
        s_idxp[t] = ix0 | (ix1 << 8) | (iy0 << 16) | (iy1 << 24);
    }
    __syncthreads();

    // phase 3: bilinear gathers from padded h-plane -> s_valb[pix][n*64+ci]
    const unsigned short* xsb = wsu + (size_t)b * BPLANE;
    for (int task = t; task < 2304; task += 512) {
        int n = task >> 8, pix = (task >> 3) & 31, cig = task & 7;
        int pk = s_idxp[pix * 9 + n];
        int ix0 = pk & 255, ix1 = (pk >> 8) & 255;
        int iy0 = (pk >> 16) & 255, iy1 = (pk >> 24) & 255;
        f32x4 g = *(const f32x4*)(s_g + (pix * 9 + n) * 4);
        const unsigned short* base = xsb + cig * 8;
        short8 v00 = *(const short8*)(base + (ix0 * 130 + iy0) * 64);
        short8 v11 = *(const short8*)(base + (ix1 * 130 + iy1) * 64);
        short8 v01 = *(const short8*)(base + (ix0 * 130 + iy1) * 64);
        short8 v10 = *(const short8*)(base + (ix1 * 130 + iy0) * 64);
        unsigned po[4];
        #pragma unroll
        for (int jp = 0; jp < 4; ++jp) {
            float e0 = g[0] * bfs2f(v00[2 * jp])     + g[1] * bfs2f(v11[2 * jp])
                     + g[2] * bfs2f(v01[2 * jp])     + g[3] * bfs2f(v10[2 * jp]);
            float e1 = g[0] * bfs2f(v00[2 * jp + 1]) + g[1] * bfs2f(v11[2 * jp + 1])
                     + g[2] * bfs2f(v01[2 * jp + 1]) + g[3] * bfs2f(v10[2 * jp + 1]);
            po[jp] = f2bf_u(e0) | (f2bf_u(e1) << 16);
        }
        *(uint4*)(s_valb + pix * 584 + n * 64 + cig * 8) = make_uint4(po[0], po[1], po[2], po[3]);
    }
    __syncthreads();

    // phase 4: MFMA contraction; wave (ct, pt): co-tile ct, px-tile pt
    {
        const int wv = t >> 6, lane = t & 63, lr = lane & 15, lg = lane >> 4;
        const int ct = wv & 3, pt = wv >> 2;
        const unsigned short* wa = wsu + WC_OFF + (ct * 16 + lr) * 576 + lg * 8;
        const unsigned short* vb = s_valb + (pt * 16 + lr) * 584 + lg * 8;
        f32x4 aE = {0,0,0,0}, aO = {0,0,0,0};
        #pragma unroll 3
        for (int kk = 0; kk < 18; kk += 2) {
            short8 a0 = *(const short8*)(wa + kk * 32);
            short8 b0 = *(const short8*)(vb + kk * 32);
            aE = __builtin_amdgcn_mfma_f32_16x16x32_bf16(a0, b0, aE, 0, 0, 0);
            short8 a1 = *(const short8*)(wa + kk * 32 + 32);
            short8 b1 = *(const short8*)(vb + kk * 32 + 32);
            aO = __builtin_amdgcn_mfma_f32_16x16x32_bf16(a1, b1, aO, 0, 0, 0);
        }
        #pragma unroll
        for (int r = 0; r < 4; ++r)
            out[(((size_t)b * 64 + ct * 16 + lg * 4 + r) * 128 + i) * 128 + j0 + pt * 16 + lr]
                = aE[r] + aO[r];
    }
}

extern "C" void kernel_launch(void* const* d_in, const int* in_sizes, int n_in,
                              void* d_out, int out_size, void* d_ws, size_t ws_size,
                              hipStream_t stream) {
    const float* x      = (const float*)d_in[0];
    const float* w_p    = (const float*)d_in[1];
    const float* b_p    = (const float*)d_in[2];
    const float* w_m    = (const float*)d_in[3];
    const float* w_ad   = (const float*)d_in[4];
    const float* w_conv = (const float*)d_in[5];
    float* outp = (float*)d_out;
    unsigned short* ws = (unsigned short*)d_ws;
    float* meta_f = (float*)(ws + META_OFF);

    prep_kernel<<<628, 256, 0, stream>>>(x, w_p, w_m, w_ad, w_conv, ws);
    meta_kernel<<<256, 512, 0, stream>>>(b_p, ws, meta_f);
    deform_kernel<<<1024, 512, 0, stream>>>(ws, meta_f, outp);
}

// Round 8
// 47.947 us; speedup vs baseline: 1.8323x; 1.0055x over previous
//
#include <hip/hip_runtime.h>
#include <hip/hip_fp16.h>
#include <math.h>

#define H 128
#define W 128
#define BATCH 2

typedef short short8 __attribute__((ext_vector_type(8)));
typedef float f32x4 __attribute__((ext_vector_type(4)));

// ws layout (ushort units):
//  XS planes: 2 x padded NHWC bf16 [2][130][130][64] (h, m split of x)
//  wc16 [64][576] (k-order n*64+ci), wmeta 2 planes [32][576] (k-order s*64+ci)
//  meta fp32 [2][128][128][32] at META_OFF
#define BPLANE 1081600
#define PLANE  2163200
#define XS_M   PLANE
#define WC_OFF (2 * PLANE)            // 4326400
#define WM_OFF (WC_OFF + 36864)       // 4363264
#define WM_PLANE 18432
#define META_OFF (WM_OFF + 2 * WM_PLANE)

__device__ __forceinline__ unsigned f2bf_u(float f) {   // RNE bf16 in low 16 bits
    union { float f; unsigned u; } v; v.f = f;
    return (v.u + 0x7FFFu + ((v.u >> 16) & 1u)) >> 16;
}
__device__ __forceinline__ float bfbits2f(unsigned lo16) {
    union { unsigned u; float f; } v; v.u = lo16 << 16;
    return v.f;
}
__device__ __forceinline__ float bfs2f(short s) {
    union { unsigned u; float f; } v; v.u = ((unsigned)(unsigned short)s) << 16;
    return v.f;
}
// 2-way bf16 split: v ~= h + m (residual ~2^-17 relative)
__device__ __forceinline__ void split2(float v, unsigned& h, unsigned& m) {
    h = f2bf_u(v);
    float r1 = v - bfbits2f(h);
    m = f2bf_u(r1);
}

__global__ __launch_bounds__(256) void prep_kernel(
    const float* __restrict__ x, const float* __restrict__ w_p,
    const float* __restrict__ w_m, const float* __restrict__ w_ad,
    const float* __restrict__ w_conv, unsigned short* __restrict__ ws)
{
    const int blk = blockIdx.x, t = threadIdx.x;
    if (blk < 520) {
        // padded split planes of x: NCHW fp32 -> 2 x NHWC bf16 [130][130][64]
        int code = blk >> 1, chalf = blk & 1;
        int b = code / 130, hrow = code % 130;
        size_t rb = ((size_t)b * 16900 + hrow * 130) * 32;   // u32 units
        unsigned* uh = (unsigned*)ws + rb;
        unsigned* um = (unsigned*)(ws + XS_M) + rb;
        if (hrow == 0 || hrow == 129) {
            for (int f = t + chalf * 2080; f < 2080 + chalf * 2080; f += 256) {
                uh[f] = 0; um[f] = 0;
            }
            return;
        }
        __shared__ float s[64 * 65];
        int h = hrow - 1;
        for (int f = t; f < 64 * 64; f += 256) {
            int ci = f >> 6, w = f & 63;
            s[ci * 65 + w] = x[((b * 64 + ci) * 128 + h) * 128 + chalf * 64 + w];
        }
        __syncthreads();
        for (int f = t; f < 2048; f += 256) {
            int w = f >> 5, cip = f & 31;
            unsigned h0, m0, h1, m1;
            split2(s[(2 * cip) * 65 + w], h0, m0);
            split2(s[(2 * cip + 1) * 65 + w], h1, m1);
            int o = (chalf * 64 + w + 1) * 32 + cip;
            uh[o] = h0 | (h1 << 16);
            um[o] = m0 | (m1 << 16);
        }
        if (chalf == 0) { if (t < 32) { uh[t] = 0; um[t] = 0; } }
        else           { if (t < 32) { int o = 129 * 32 + t; uh[o] = 0; um[o] = 0; } }
    } else if (blk < 556) {
        // w_conv reorder to k = n*64 + ci, bf16
        int q = (blk - 520) * 256 + t;           // 0..9215
        int co = q / 144, rem = q % 144, n = rem >> 4, cig = rem & 15;
        const float* src = w_conv + co * 576;
        ushort4 r;
        r.x = (unsigned short)f2bf_u(src[(cig * 4 + 0) * 9 + n]);
        r.y = (unsigned short)f2bf_u(src[(cig * 4 + 1) * 9 + n]);
        r.z = (unsigned short)f2bf_u(src[(cig * 4 + 2) * 9 + n]);
        r.w = (unsigned short)f2bf_u(src[(cig * 4 + 3) * 9 + n]);
        *(ushort4*)(ws + WC_OFF + co * 576 + n * 64 + cig * 4) = r;
    } else {
        // meta weights: k-order s*64+ci, 2-way split, rows 30/31 zero
        int q = (blk - 556) * 256 + t;           // 0..18431
        int oc = q / 576, k = q % 576;
        int s = k >> 6, ci = k & 63;
        float v = 0.f;
        if (oc < 18)      v = w_p[oc * 576 + ci * 9 + s];
        else if (oc < 21) v = w_ad[(oc - 18) * 576 + ci * 9 + s];
        else if (oc < 30) v = w_m[(oc - 21) * 576 + ci * 9 + s];
        unsigned hh, mm; split2(v, hh, mm);
        ws[WM_OFF + q] = (unsigned short)hh;
        ws[WM_OFF + WM_PLANE + q] = (unsigned short)mm;
    }
}

// meta_kernel: one block per output row. Weights in LDS (64 rows x 584 pad = 73 KB),
// 8 waves x 16 px, full K per wave, 3-pass split MFMA (h*h + h*m + m*h).
__global__ __launch_bounds__(512, 2) void meta_kernel(
    const float* __restrict__ b_p, const unsigned short* __restrict__ wsu,
    float* __restrict__ meta)
{
    __shared__ __align__(16) unsigned short s_w[64 * 584];   // 74752 B
    const int t = threadIdx.x;
    const int d = blockIdx.x;
    const int l = (d & 7) * 32 + (d >> 3);   // XCD-contiguous rows
    const int b = l >> 7, i = l & 127;

    #pragma unroll
    for (int it = 0; it < 9; ++it) {
        int chunk = it * 512 + t;            // 4608 chunks of 8 ushort
        int r = chunk / 72, c8 = chunk % 72;
        *(short8*)(s_w + r * 584 + c8 * 8) =
            *(const short8*)(wsu + WM_OFF + chunk * 8);
    }
    __syncthreads();

    const int wv = t >> 6, lane = t & 63, lr = lane & 15, lg = lane >> 4;
    const int px = wv * 16 + lr;
    const unsigned short* xsb = wsu + (size_t)b * BPLANE;

    f32x4 aA0 = {0,0,0,0}, aB0 = {0,0,0,0}, aA1 = {0,0,0,0}, aB1 = {0,0,0,0};
    #pragma unroll
    for (int kk = 0; kk < 18; ++kk) {
        const int s = kk >> 1;
        const unsigned short* bp = xsb + ((i + s / 3) * 130 + (px + s % 3)) * 64
                                   + ((kk & 1) << 5) + lg * 8;
        short8 bh = *(const short8*)(bp);
        short8 bm = *(const short8*)(bp + XS_M);
        const unsigned short* w0 = s_w + lr * 584 + kk * 32 + lg * 8;
        short8 ah0 = *(const short8*)(w0);
        short8 am0 = *(const short8*)(w0 + 32 * 584);
        const unsigned short* w1 = w0 + 16 * 584;
        short8 ah1 = *(const short8*)(w1);
        short8 am1 = *(const short8*)(w1 + 32 * 584);
        aA0 = __builtin_amdgcn_mfma_f32_16x16x32_bf16(ah0, bh, aA0, 0, 0, 0);
        aB0 = __builtin_amdgcn_mfma_f32_16x16x32_bf16(ah0, bm, aB0, 0, 0, 0);
        aA0 = __builtin_amdgcn_mfma_f32_16x16x32_bf16(am0, bh, aA0, 0, 0, 0);
        aA1 = __builtin_amdgcn_mfma_f32_16x16x32_bf16(ah1, bh, aA1, 0, 0, 0);
        aB1 = __builtin_amdgcn_mfma_f32_16x16x32_bf16(ah1, bm, aB1, 0, 0, 0);
        aA1 = __builtin_amdgcn_mfma_f32_16x16x32_bf16(am1, bh, aA1, 0, 0, 0);
    }

    float* mb = meta + (((size_t)b * 128 + i) * 128 + px) * 32;
    {
        const float4 bq = *(const float4*)(b_p + lg * 4);
        f32x4 o0;
        o0[0] = aA0[0] + aB0[0] + bq.x;
        o0[1] = aA0[1] + aB0[1] + bq.y;
        o0[2] = aA0[2] + aB0[2] + bq.z;
        o0[3] = aA0[3] + aB0[3] + bq.w;
        *(f32x4*)(mb + lg * 4) = o0;
    }
    {
        f32x4 o1;
        #pragma unroll
        for (int r = 0; r < 4; ++r) {
            int oc = 16 + lg * 4 + r;
            float v = aA1[r] + aB1[r];
            if (oc < 18)      v += b_p[oc];
            else if (oc < 21) v = 1.f - 1.f / (1.f + expf(-v));
            else              v = 1.f / (1.f + expf(-v));
            o1[r] = v;
        }
        *(f32x4*)(mb + 16 + lg * 4) = o1;
    }
}

// deform_kernel: 32 px/block, 512 thr, slim LDS 40832 B -> 4 blocks/CU,
// __launch_bounds__(512,8) targets VGPR<=64 -> 32 waves/CU.
__global__ __launch_bounds__(512, 8) void deform_kernel(
    const unsigned short* __restrict__ wsu, const float* __restrict__ meta,
    float* __restrict__ out)
{
    __shared__ __align__(16) char smem[40832];
    unsigned short* s_valb = (unsigned short*)smem;       // [32][584] bf16
    __half2* s_gh = (__half2*)(smem + 37376);             // [288][2] half2 (g0g1, g2g3)
    int* s_idxp = (int*)(smem + 39680);                   // [288]

    const int t = threadIdx.x;
    const int d = blockIdx.x;
    const int l = (d & 7) * 128 + (d >> 3);   // XCD-contiguous bands (match meta_kernel)
    const int jb = l & 3, i = (l >> 2) & 127, b = l >> 9;
    const int j0 = jb * 32;

    // phase 2: sampling corners + premultiplied bilinear*modulation weights
    // (meta read direct from global; buffer is XCD-L2-local)
    if (t < 288) {
        int pix = t / 9, n = t % 9;
        int ki = n / 3, kj = n % 3;
        const float* mrow = meta + (((size_t)b * 128 + i) * 128 + j0 + pix) * 32;
        float adb  = mrow[18 + kj];
        float offx = mrow[n];
        float offy = mrow[9 + n];
        float msig = mrow[21 + n];
        float pnx = (float)(ki - 1), pny = (float)(kj - 1);
        float pxc = (float)(i + 1)        + pnx + offx + 2.f * adb * pnx;
        float pyc = (float)(j0 + pix + 1) + pny + offy + 2.f * adb * pny;

        float flx = floorf(pxc), fly = floorf(pyc);
        int ix0 = (int)fminf(fmaxf(flx,       0.f), 129.f);
        int ix1 = (int)fminf(fmaxf(flx + 1.f, 0.f), 129.f);
        int iy0 = (int)fminf(fmaxf(fly,       0.f), 129.f);
        int iy1 = (int)fminf(fmaxf(fly + 1.f, 0.f), 129.f);

        float ptx = (pxc < 1.f || pxc > 128.f) ? flx : pxc;
        float pty = (pyc < 1.f || pyc > 128.f) ? fly : pyc;
        ptx = fminf(fmaxf(ptx, 0.f), 129.f);
        pty = fminf(fmaxf(pty, 0.f), 129.f);

        float wxl = 1.f + (float)ix0 - ptx;
        float wxr = 1.f - ((float)ix1 - ptx);
        float wyl = 1.f + (float)iy0 - pty;
        float wyr = 1.f - ((float)iy1 - pty);

        float mm = msig * (adb - 0.5f) * 4.f;

        s_gh[t * 2 + 0] = __floats2half2_rn(wxl * wyl * mm, wxr * wyr * mm);
        s_gh[t * 2 + 1] = __floats2half2_rn(wxl * wyr * mm, wxr * wyl * mm);
        s_idxp[t] = ix0 | (ix1 << 8) | (iy0 << 16) | (iy1 << 24);
    }
    __syncthreads();

    // phase 3: bilinear gathers from padded h-plane -> s_valb[pix][n*64+ci]
    const unsigned short* xsb = wsu + (size_t)b * BPLANE;
    #define GATHER(TASK) do {                                                     \
        int task = (TASK);                                                        \
        int n = task >> 8, pix = (task >> 3) & 31, cig = task & 7;                \
        int pk = s_idxp[pix * 9 + n];                                             \
        int ix0 = pk & 255, ix1 = (pk >> 8) & 255;                                \
        int iy0 = (pk >> 16) & 255, iy1 = (pk >> 24) & 255;                       \
        const unsigned short* base = xsb + cig * 8;                               \
        short8 v00 = *(const short8*)(base + (ix0 * 130 + iy0) * 64);             \
        short8 v11 = *(const short8*)(base + (ix1 * 130 + iy1) * 64);             \
        short8 v01 = *(const short8*)(base + (ix0 * 130 + iy1) * 64);             \
        short8 v10 = *(const short8*)(base + (ix1 * 130 + iy0) * 64);             \
        float2 g01 = __half22float2(s_gh[(pix * 9 + n) * 2 + 0]);                 \
        float2 g23 = __half22float2(s_gh[(pix * 9 + n) * 2 + 1]);                 \
        unsigned po[4];                                                           \
        _Pragma("unroll")                                                         \
        for (int jp = 0; jp < 4; ++jp) {                                          \
            float e0 = g01.x * bfs2f(v00[2 * jp])     + g01.y * bfs2f(v11[2 * jp])\
                     + g23.x * bfs2f(v01[2 * jp])     + g23.y * bfs2f(v10[2 * jp]);\
            float e1 = g01.x * bfs2f(v00[2 * jp + 1]) + g01.y * bfs2f(v11[2 * jp + 1])\
                     + g23.x * bfs2f(v01[2 * jp + 1]) + g23.y * bfs2f(v10[2 * jp + 1]);\
            po[jp] = f2bf_u(e0) | (f2bf_u(e1) << 16);                             \
        }                                                                         \
        *(uint4*)(s_valb + pix * 584 + n * 64 + cig * 8)                          \
            = make_uint4(po[0], po[1], po[2], po[3]);                             \
    } while (0)

    #pragma unroll
    for (int it = 0; it < 4; ++it) GATHER(t + it * 512);
    if (t < 256) GATHER(t + 2048);
    #undef GATHER
    __syncthreads();

    // phase 4: MFMA contraction; wave (ct, pt): co-tile ct, px-tile pt
    {
        const int wv = t >> 6, lane = t & 63, lr = lane & 15, lg = lane >> 4;
        const int ct = wv & 3, pt = wv >> 2;
        const unsigned short* wa = wsu + WC_OFF + (ct * 16 + lr) * 576 + lg * 8;
        const unsigned short* vb = s_valb + (pt * 16 + lr) * 584 + lg * 8;
        f32x4 aE = {0,0,0,0}, aO = {0,0,0,0};
        #pragma unroll 3
        for (int kk = 0; kk < 18; kk += 2) {
            short8 a0 = *(const short8*)(wa + kk * 32);
            short8 b0 = *(const short8*)(vb + kk * 32);
            aE = __builtin_amdgcn_mfma_f32_16x16x32_bf16(a0, b0, aE, 0, 0, 0);
            short8 a1 = *(const short8*)(wa + kk * 32 + 32);
            short8 b1 = *(const short8*)(vb + kk * 32 + 32);
            aO = __builtin_amdgcn_mfma_f32_16x16x32_bf16(a1, b1, aO, 0, 0, 0);
        }
        #pragma unroll
        for (int r = 0; r < 4; ++r)
            out[(((size_t)b * 64 + ct * 16 + lg * 4 + r) * 128 + i) * 128 + j0 + pt * 16 + lr]
                = aE[r] + aO[r];
    }
}

extern "C" void kernel_launch(void* const* d_in, const int* in_sizes, int n_in,
                              void* d_out, int out_size, void* d_ws, size_t ws_size,
                              hipStream_t stream) {
    const float* x      = (const float*)d_in[0];
    const float* w_p    = (const float*)d_in[1];
    const float* b_p    = (const float*)d_in[2];
    const float* w_m    = (const float*)d_in[3];
    const float* w_ad   = (const float*)d_in[4];
    const float* w_conv = (const float*)d_in[5];
    float* outp = (float*)d_out;
    unsigned short* ws = (unsigned short*)d_ws;
    float* meta_f = (float*)(ws + META_OFF);

    prep_kernel<<<628, 256, 0, stream>>>(x, w_p, w_m, w_ad, w_conv, ws);
    meta_kernel<<<256, 512, 0, stream>>>(b_p, ws, meta_f);
    deform_kernel<<<1024, 512, 0, stream>>>(ws, meta_f, outp);
}